// Round 4
// baseline (537.137 us; speedup 1.0000x reference)
//
#include <hip/hip_runtime.h>
#include <stdint.h>

typedef unsigned short bf16_t;

constexpr int kNN   = 100000;
constexpr int kNE   = 1600000;
constexpr int kFEAT = 256;
constexpr int kHID  = 128;
constexpr int kOUT  = 64;
constexpr int kNB   = 10000;
constexpr float kEPS = 1e-5f;

constexpr int kEPB  = 4096;                       // edges per hist/scatter block
constexpr int kNBLK = (kNE + kEPB - 1) / kEPB;    // 391
constexpr int kNBUK = (kNN + 511) / 512;          // 196 coarse buckets (512 nodes each)

typedef __attribute__((ext_vector_type(8))) short short8v;
typedef __attribute__((ext_vector_type(4))) float f32x4;

__device__ __forceinline__ float bf2f(bf16_t u) {
    union { uint32_t i; float f; } v; v.i = ((uint32_t)u) << 16; return v.f;
}
__device__ __forceinline__ bf16_t f2bf(float f) {
    uint32_t u = __float_as_uint(f);
    uint32_t r = (u + 0x7FFFu + ((u >> 16) & 1u)) >> 16;
    return (bf16_t)r;
}
__device__ __forceinline__ float lo16(uint32_t u) {
    union { uint32_t i; float f; } v; v.i = u << 16; return v.f;
}
__device__ __forceinline__ float hi16(uint32_t u) {
    union { uint32_t i; float f; } v; v.i = u & 0xFFFF0000u; return v.f;
}

#define ACC8(u) do { \
    acc[0] += lo16((u).x); acc[1] += hi16((u).x); \
    acc[2] += lo16((u).y); acc[3] += hi16((u).y); \
    acc[4] += lo16((u).z); acc[5] += hi16((u).z); \
    acc[6] += lo16((u).w); acc[7] += hi16((u).w); } while (0)

// flags[0]: 1 if float tensors are bf16, 0 if fp32.  flags[1]: 1 if edge_index int64.
__global__ void k_probe(const uint32_t* __restrict__ feat, const uint32_t* __restrict__ ei,
                        int* __restrict__ flags) {
    int l = threadIdx.x;   // 64 lanes
    int good = 0;
    for (int j = l; j < 256; j += 64) {
        uint32_t e = (feat[j] >> 7) & 0xFFu;
        if (e >= 100u && e <= 132u) good++;
    }
    for (int o = 32; o; o >>= 1) good += __shfl_xor(good, o);
    int zeros = 0;
    for (int j = l; j < 128; j += 64) zeros += (ei[2 * j + 1] == 0u) ? 1 : 0;
    for (int o = 32; o; o >>= 1) zeros += __shfl_xor(zeros, o);
    if (l == 0) {
        flags[0] = (good > 128) ? 1 : 0;
        flags[1] = (zeros > 64) ? 1 : 0;
    }
}

// -------- graph build: two-level multisplit (no global atomics) --------

__global__ void k_hist1(const int* __restrict__ ei, const int* __restrict__ flags,
                        unsigned int* __restrict__ counts) {
    __shared__ unsigned int lh[kNBUK];
    int t = threadIdx.x;
    for (int i = t; i < kNBUK; i += 256) lh[i] = 0u;
    __syncthreads();
    int i64 = flags[1];
    int base = blockIdx.x * kEPB;
    for (int k = 0; k < 16; k++) {
        int e = base + k * 256 + t;
        if (e < kNE) {
            int d = i64 ? ei[2 * (kNE + e)] : ei[kNE + e];
            atomicAdd(&lh[d >> 9], 1u);
        }
    }
    __syncthreads();
    for (int i = t; i < kNBUK; i += 256) counts[(size_t)i * kNBLK + blockIdx.x] = lh[i];
}

// bucket totals -> exclusive bases; also zero stats
__global__ void k_scanA(const unsigned int* __restrict__ counts, unsigned int* __restrict__ base,
                        float* __restrict__ stats) {
    __shared__ unsigned int ss[256];
    int t = threadIdx.x;
    for (int i = t; i < 384; i += 256) stats[i] = 0.f;
    unsigned int tot = 0u;
    if (t < kNBUK) {
        const unsigned int* row = counts + (size_t)t * kNBLK;
        for (int j = 0; j < kNBLK; j++) tot += row[j];
    }
    ss[t] = tot;
    __syncthreads();
    for (int o = 1; o < 256; o <<= 1) {
        unsigned int x = (t >= o) ? ss[t - o] : 0u;
        __syncthreads();
        ss[t] += x;
        __syncthreads();
    }
    if (t < kNBUK) base[t] = ss[t] - tot;   // exclusive
    if (t == 0) base[kNBUK] = ss[255];      // == kNE
}

// per-(bucket,block) offsets
__global__ void k_scanB(const unsigned int* __restrict__ counts, const unsigned int* __restrict__ base,
                        unsigned int* __restrict__ off) {
    __shared__ unsigned int ss[64];
    int b = blockIdx.x, t = threadIdx.x;
    unsigned int run = base[b];
    for (int c0 = 0; c0 < kNBLK; c0 += 64) {
        int idx = c0 + t;
        unsigned int v = (idx < kNBLK) ? counts[(size_t)b * kNBLK + idx] : 0u;
        ss[t] = v;
        __syncthreads();
        for (int o = 1; o < 64; o <<= 1) {
            unsigned int x = (t >= o) ? ss[t - o] : 0u;
            __syncthreads();
            ss[t] += x;
            __syncthreads();
        }
        if (idx < kNBLK) off[(size_t)b * kNBLK + idx] = run + ss[t] - v;
        unsigned int ctot = ss[63];
        __syncthreads();
        run += ctot;
    }
}

// coarse scatter: packed (src | dlocal<<17), bucket-grouped runs, LDS cursors only
__global__ void k_scatter1(const int* __restrict__ ei, const int* __restrict__ flags,
                           const unsigned int* __restrict__ off, unsigned int* __restrict__ pairs) {
    __shared__ unsigned int lcur[kNBUK];
    int t = threadIdx.x;
    for (int i = t; i < kNBUK; i += 256) lcur[i] = off[(size_t)i * kNBLK + blockIdx.x];
    __syncthreads();
    int i64 = flags[1];
    int base = blockIdx.x * kEPB;
    for (int k = 0; k < 16; k++) {
        int e = base + k * 256 + t;
        if (e < kNE) {
            int s, d;
            if (i64) { s = ei[2 * e]; d = ei[2 * (kNE + e)]; }
            else     { s = ei[e];     d = ei[kNE + e]; }
            unsigned int p = atomicAdd(&lcur[d >> 9], 1u);
            pairs[p] = (unsigned int)s | ((unsigned int)(d & 511) << 17);
        }
    }
}

// fine scatter: one block per bucket; exact per-node CSR + deg/dinv/cursor
__global__ void __launch_bounds__(1024) k_scatter2(const unsigned int* __restrict__ pairs,
                        const unsigned int* __restrict__ base, unsigned int* __restrict__ deg,
                        float* __restrict__ dinv, unsigned int* __restrict__ cursor,
                        int* __restrict__ sorted) {
    __shared__ unsigned int hist[512], sc[512], lcur[512];
    int b = blockIdx.x, t = threadIdx.x;
    unsigned int gb = base[b];
    int cnt = (int)(base[b + 1] - gb);
    if (t < 512) hist[t] = 0u;
    __syncthreads();
    for (int i = t; i < cnt; i += 1024) atomicAdd(&hist[pairs[gb + i] >> 17], 1u);
    __syncthreads();
    if (t < 512) sc[t] = hist[t];
    __syncthreads();
    for (int o = 1; o < 512; o <<= 1) {
        unsigned int x = 0u;
        if (t < 512 && t >= o) x = sc[t - o];
        __syncthreads();
        if (t < 512) sc[t] += x;
        __syncthreads();
    }
    if (t < 512) {
        lcur[t] = gb + sc[t] - hist[t];
        int node = b * 512 + t;
        if (node < kNN) {
            unsigned int dg = hist[t] + 1u;   // + self loop
            deg[node] = dg;
            dinv[node] = rsqrtf((float)dg);
            cursor[node] = gb + sc[t];        // end of node's slice
        }
    }
    __syncthreads();
    for (int i = t; i < cnt; i += 1024) {
        unsigned int pk = pairs[gb + i];
        unsigned int slot = atomicAdd(&lcur[pk >> 17], 1u);
        sorted[slot] = (int)(pk & 0x1FFFFu);
    }
}

// -------- weights pre-swizzle (merged W1 + W2) --------
__global__ void k_prepw(const void* __restrict__ W1, const void* __restrict__ W2,
                        const int* __restrict__ flags, bf16_t* __restrict__ Wz1,
                        bf16_t* __restrict__ Wz2) {
    int gid = blockIdx.x * 256 + threadIdx.x;
    int isbf = flags[0];
    if (gid < 4096) {                 // W1: 8 k-steps x 8 n-frags x 64 lanes
        int idx = gid;
        int l = idx & 63, j = (idx >> 6) & 7, t = idx >> 9;
        int col = j * 16 + (l & 15);
        int kb = t * 32 + (l >> 4) * 8;
        bf16_t o[8];
        if (isbf) {
            const bf16_t* Wb = (const bf16_t*)W1;
            #pragma unroll
            for (int i = 0; i < 8; i++) o[i] = Wb[(size_t)(kb + i) * kHID + col];
        } else {
            const float* Wf = (const float*)W1;
            #pragma unroll
            for (int i = 0; i < 8; i++) o[i] = f2bf(Wf[(size_t)(kb + i) * kHID + col]);
        }
        uint4 w;
        w.x = (uint32_t)o[0] | ((uint32_t)o[1] << 16);
        w.y = (uint32_t)o[2] | ((uint32_t)o[3] << 16);
        w.z = (uint32_t)o[4] | ((uint32_t)o[5] << 16);
        w.w = (uint32_t)o[6] | ((uint32_t)o[7] << 16);
        *(uint4*)(Wz1 + (size_t)idx * 8) = w;
    } else if (gid < 4096 + 1024) {   // W2: 4 k-steps x 4 n-frags x 64 lanes
        int idx = gid - 4096;
        int l = idx & 63, j = (idx >> 6) & 3, t = idx >> 8;
        int col = j * 16 + (l & 15);
        int kb = t * 32 + (l >> 4) * 8;
        bf16_t o[8];
        if (isbf) {
            const bf16_t* Wb = (const bf16_t*)W2;
            #pragma unroll
            for (int i = 0; i < 8; i++) o[i] = Wb[(size_t)(kb + i) * kOUT + col];
        } else {
            const float* Wf = (const float*)W2;
            #pragma unroll
            for (int i = 0; i < 8; i++) o[i] = f2bf(Wf[(size_t)(kb + i) * kOUT + col]);
        }
        uint4 w;
        w.x = (uint32_t)o[0] | ((uint32_t)o[1] << 16);
        w.y = (uint32_t)o[2] | ((uint32_t)o[3] << 16);
        w.z = (uint32_t)o[4] | ((uint32_t)o[5] << 16);
        w.w = (uint32_t)o[6] | ((uint32_t)o[7] << 16);
        *(uint4*)(Wz2 + (size_t)idx * 8) = w;
    }
}

// -------- layer 1 GEMM (MFMA): H = dinv * (A @ W1), bf16 out --------
__global__ void k_gemm1(const void* __restrict__ A, const bf16_t* __restrict__ Wz,
                        const float* __restrict__ dinv, bf16_t* __restrict__ H,
                        const int* __restrict__ flags) {
    int isbf = flags[0];
    int wv = threadIdx.x >> 6;
    int l  = threadIdx.x & 63;
    int kgrp = l >> 4;
    int rbase = blockIdx.x * 128 + wv * 32;
    int arow0 = rbase + (l & 15);
    int arow1 = arow0 + 16;
    const bf16_t* Ab = (const bf16_t*)A;
    const float*  Af = (const float*)A;
    const short8v* Wv = (const short8v*)Wz;

    f32x4 acc[2][8];
    #pragma unroll
    for (int m = 0; m < 2; m++)
        #pragma unroll
        for (int j = 0; j < 8; j++)
            acc[m][j] = (f32x4){0.f, 0.f, 0.f, 0.f};

    #pragma unroll
    for (int t = 0; t < 8; t++) {
        int kbase = t * 32 + kgrp * 8;
        short8v a0, a1;
        #pragma unroll
        for (int i = 0; i < 8; i++) { a0[i] = 0; a1[i] = 0; }
        if (arow0 < kNN) {
            if (isbf) {
                a0 = *(const short8v*)(Ab + (size_t)arow0 * kFEAT + kbase);
            } else {
                const float* p = Af + (size_t)arow0 * kFEAT + kbase;
                #pragma unroll
                for (int i = 0; i < 8; i++) a0[i] = (short)f2bf(p[i]);
            }
        }
        if (arow1 < kNN) {
            if (isbf) {
                a1 = *(const short8v*)(Ab + (size_t)arow1 * kFEAT + kbase);
            } else {
                const float* p = Af + (size_t)arow1 * kFEAT + kbase;
                #pragma unroll
                for (int i = 0; i < 8; i++) a1[i] = (short)f2bf(p[i]);
            }
        }
        #pragma unroll
        for (int j = 0; j < 8; j++) {
            short8v b = Wv[(t * 8 + j) * 64 + l];
            acc[0][j] = __builtin_amdgcn_mfma_f32_16x16x32_bf16(a0, b, acc[0][j], 0, 0, 0);
            acc[1][j] = __builtin_amdgcn_mfma_f32_16x16x32_bf16(a1, b, acc[1][j], 0, 0, 0);
        }
    }

    #pragma unroll
    for (int m = 0; m < 2; m++) {
        #pragma unroll
        for (int r = 0; r < 4; r++) {
            int orow = rbase + m * 16 + kgrp * 4 + r;
            if (orow < kNN) {
                float dn = dinv[orow];
                bf16_t* hp = H + (size_t)orow * kHID + (l & 15);
                #pragma unroll
                for (int j = 0; j < 8; j++) hp[j * 16] = f2bf(acc[m][j][r] * dn);
            }
        }
    }
}

// A1 = dinv*(sum_src H[s] + H[n]) + b1, fused BN stats.
// 16-lane group per node, dwordx4 gathers, shfl-broadcast indices, grid-stride.
__global__ void k_agg1(const bf16_t* __restrict__ H, const int* __restrict__ sorted,
                       const unsigned int* __restrict__ cursor, const unsigned int* __restrict__ deg,
                       const float* __restrict__ dinv, const void* __restrict__ bias,
                       const int* __restrict__ flags, float* __restrict__ Out,
                       float* __restrict__ stats) {
    __shared__ float ss[256];   // [0..128) sum, [128..256) sumsq
    int t = threadIdx.x;
    ss[t] = 0.f;
    __syncthreads();
    int g16 = t & 15;
    int grp = t >> 4;           // 16 nodes per block-tile
    int c0 = g16 * 8;           // my 8 channels
    float bv[8];
    if (flags[0]) {
        const bf16_t* bb = (const bf16_t*)bias;
        #pragma unroll
        for (int j = 0; j < 8; j++) bv[j] = bf2f(bb[c0 + j]);
    } else {
        const float* bf = (const float*)bias;
        #pragma unroll
        for (int j = 0; j < 8; j++) bv[j] = bf[c0 + j];
    }
    for (int n0 = blockIdx.x * 16; n0 < kNN; n0 += gridDim.x * 16) {
        int n = n0 + grp;       // kNN % 16 == 0, always valid
        float acc[8];
        uint4 hs = *(const uint4*)(H + (size_t)n * kHID + c0);
        acc[0] = lo16(hs.x); acc[1] = hi16(hs.x);
        acc[2] = lo16(hs.y); acc[3] = hi16(hs.y);
        acc[4] = lo16(hs.z); acc[5] = hi16(hs.z);
        acc[6] = lo16(hs.w); acc[7] = hi16(hs.w);
        unsigned int e1 = cursor[n];
        int cnt = (int)(deg[n] - 1u);
        unsigned int e0 = e1 - (unsigned int)cnt;
        for (int base = 0; base < cnt; base += 16) {
            int idx = 0;
            if (base + g16 < cnt) idx = sorted[e0 + base + g16];
            int m = cnt - base; if (m > 16) m = 16;
            int j = 0;
            for (; j + 4 <= m; j += 4) {
                int s0 = __shfl(idx, j, 16);
                int s1 = __shfl(idx, j + 1, 16);
                int s2 = __shfl(idx, j + 2, 16);
                int s3 = __shfl(idx, j + 3, 16);
                uint4 u0 = *(const uint4*)(H + (size_t)s0 * kHID + c0);
                uint4 u1 = *(const uint4*)(H + (size_t)s1 * kHID + c0);
                uint4 u2 = *(const uint4*)(H + (size_t)s2 * kHID + c0);
                uint4 u3 = *(const uint4*)(H + (size_t)s3 * kHID + c0);
                ACC8(u0); ACC8(u1); ACC8(u2); ACC8(u3);
            }
            for (; j < m; j++) {
                int s = __shfl(idx, j, 16);
                uint4 u = *(const uint4*)(H + (size_t)s * kHID + c0);
                ACC8(u);
            }
        }
        float dn = dinv[n];
        float o[8];
        #pragma unroll
        for (int j = 0; j < 8; j++) o[j] = acc[j] * dn + bv[j];
        float4 w0 = {o[0], o[1], o[2], o[3]};
        float4 w1 = {o[4], o[5], o[6], o[7]};
        *(float4*)(Out + (size_t)n * kHID + c0) = w0;
        *(float4*)(Out + (size_t)n * kHID + c0 + 4) = w1;
        #pragma unroll
        for (int j = 0; j < 8; j++) {
            atomicAdd(&ss[c0 + j], o[j]);
            atomicAdd(&ss[128 + c0 + j], o[j] * o[j]);
        }
    }
    __syncthreads();
    atomicAdd(&stats[t], ss[t]);
}

// fold BN1 stats into per-channel scale/shift
__global__ void k_bnprep(const float* __restrict__ stats, const void* __restrict__ gamma,
                         const void* __restrict__ beta, const int* __restrict__ flags,
                         float* __restrict__ bnp) {
    int c = threadIdx.x;   // 128
    float mu = stats[c] * (1.f / kNN);
    float var = stats[128 + c] * (1.f / kNN) - mu * mu;
    float rs = rsqrtf(var + kEPS);
    float g, b;
    if (flags[0]) { g = bf2f(((const bf16_t*)gamma)[c]); b = bf2f(((const bf16_t*)beta)[c]); }
    else          { g = ((const float*)gamma)[c];        b = ((const float*)beta)[c]; }
    float sc = rs * g;
    bnp[c] = sc;
    bnp[128 + c] = b - mu * sc;
}

// layer 2 GEMM with fused BN1+ReLU on the fly. Reads a1 (fp32), writes h2 rows
// embedded at a1 row starts (each wave reads exactly the rows it later writes).
__global__ void k_gemm2(const float* A, const bf16_t* __restrict__ Wz,
                        const float* __restrict__ dinv, const float* __restrict__ bnp,
                        bf16_t* H /* = (bf16_t*)A, row stride 256 elems */) {
    int wv = threadIdx.x >> 6;
    int l  = threadIdx.x & 63;
    int kgrp = l >> 4;
    int rbase = blockIdx.x * 128 + wv * 32;
    int arow0 = rbase + (l & 15);
    int arow1 = arow0 + 16;
    const short8v* Wv = (const short8v*)Wz;

    f32x4 acc[2][4];
    #pragma unroll
    for (int m = 0; m < 2; m++)
        #pragma unroll
        for (int j = 0; j < 4; j++)
            acc[m][j] = (f32x4){0.f, 0.f, 0.f, 0.f};

    #pragma unroll
    for (int t = 0; t < 4; t++) {
        int kbase = t * 32 + kgrp * 8;
        float4 sa = *(const float4*)(bnp + kbase);
        float4 sb = *(const float4*)(bnp + kbase + 4);
        float4 ha = *(const float4*)(bnp + 128 + kbase);
        float4 hb = *(const float4*)(bnp + 128 + kbase + 4);
        short8v a0, a1;
        #pragma unroll
        for (int i = 0; i < 8; i++) { a0[i] = 0; a1[i] = 0; }
        if (arow0 < kNN) {
            float4 f0 = *(const float4*)(A + (size_t)arow0 * kHID + kbase);
            float4 f1 = *(const float4*)(A + (size_t)arow0 * kHID + kbase + 4);
            float v;
            v = f0.x * sa.x + ha.x; a0[0] = (short)f2bf(v > 0.f ? v : 0.f);
            v = f0.y * sa.y + ha.y; a0[1] = (short)f2bf(v > 0.f ? v : 0.f);
            v = f0.z * sa.z + ha.z; a0[2] = (short)f2bf(v > 0.f ? v : 0.f);
            v = f0.w * sa.w + ha.w; a0[3] = (short)f2bf(v > 0.f ? v : 0.f);
            v = f1.x * sb.x + hb.x; a0[4] = (short)f2bf(v > 0.f ? v : 0.f);
            v = f1.y * sb.y + hb.y; a0[5] = (short)f2bf(v > 0.f ? v : 0.f);
            v = f1.z * sb.z + hb.z; a0[6] = (short)f2bf(v > 0.f ? v : 0.f);
            v = f1.w * sb.w + hb.w; a0[7] = (short)f2bf(v > 0.f ? v : 0.f);
        }
        if (arow1 < kNN) {
            float4 f0 = *(const float4*)(A + (size_t)arow1 * kHID + kbase);
            float4 f1 = *(const float4*)(A + (size_t)arow1 * kHID + kbase + 4);
            float v;
            v = f0.x * sa.x + ha.x; a1[0] = (short)f2bf(v > 0.f ? v : 0.f);
            v = f0.y * sa.y + ha.y; a1[1] = (short)f2bf(v > 0.f ? v : 0.f);
            v = f0.z * sa.z + ha.z; a1[2] = (short)f2bf(v > 0.f ? v : 0.f);
            v = f0.w * sa.w + ha.w; a1[3] = (short)f2bf(v > 0.f ? v : 0.f);
            v = f1.x * sb.x + hb.x; a1[4] = (short)f2bf(v > 0.f ? v : 0.f);
            v = f1.y * sb.y + hb.y; a1[5] = (short)f2bf(v > 0.f ? v : 0.f);
            v = f1.z * sb.z + hb.z; a1[6] = (short)f2bf(v > 0.f ? v : 0.f);
            v = f1.w * sb.w + hb.w; a1[7] = (short)f2bf(v > 0.f ? v : 0.f);
        }
        #pragma unroll
        for (int j = 0; j < 4; j++) {
            short8v b = Wv[(t * 4 + j) * 64 + l];
            acc[0][j] = __builtin_amdgcn_mfma_f32_16x16x32_bf16(a0, b, acc[0][j], 0, 0, 0);
            acc[1][j] = __builtin_amdgcn_mfma_f32_16x16x32_bf16(a1, b, acc[1][j], 0, 0, 0);
        }
    }

    #pragma unroll
    for (int m = 0; m < 2; m++) {
        #pragma unroll
        for (int r = 0; r < 4; r++) {
            int orow = rbase + m * 16 + kgrp * 4 + r;
            if (orow < kNN) {
                float dn = dinv[orow];
                bf16_t* hp = H + (size_t)orow * 256 + (l & 15);   // stride 256 elems = a1 row
                #pragma unroll
                for (int j = 0; j < 4; j++) hp[j * 16] = f2bf(acc[m][j][r] * dn);
            }
        }
    }
}

// layer-2 aggregation, 8-lane groups, h2 row stride 256 elems, fused BN2 stats
__global__ void k_agg2(const bf16_t* __restrict__ H, const int* __restrict__ sorted,
                       const unsigned int* __restrict__ cursor, const unsigned int* __restrict__ deg,
                       const float* __restrict__ dinv, const void* __restrict__ bias,
                       const int* __restrict__ flags, float* __restrict__ Out,
                       float* __restrict__ stats) {
    __shared__ float ss[128];   // [0..64) sum, [64..128) sumsq
    int t = threadIdx.x;
    if (t < 128) ss[t] = 0.f;
    __syncthreads();
    int g8 = t & 7;
    int grp = t >> 3;           // 32 nodes per block-tile
    int c0 = g8 * 8;
    float bv[8];
    if (flags[0]) {
        const bf16_t* bb = (const bf16_t*)bias;
        #pragma unroll
        for (int j = 0; j < 8; j++) bv[j] = bf2f(bb[c0 + j]);
    } else {
        const float* bf = (const float*)bias;
        #pragma unroll
        for (int j = 0; j < 8; j++) bv[j] = bf[c0 + j];
    }
    for (int n0 = blockIdx.x * 32; n0 < kNN; n0 += gridDim.x * 32) {
        int n = n0 + grp;       // kNN % 32 == 0
        float acc[8];
        uint4 hs = *(const uint4*)(H + (size_t)n * 256 + c0);
        acc[0] = lo16(hs.x); acc[1] = hi16(hs.x);
        acc[2] = lo16(hs.y); acc[3] = hi16(hs.y);
        acc[4] = lo16(hs.z); acc[5] = hi16(hs.z);
        acc[6] = lo16(hs.w); acc[7] = hi16(hs.w);
        unsigned int e1 = cursor[n];
        int cnt = (int)(deg[n] - 1u);
        unsigned int e0 = e1 - (unsigned int)cnt;
        for (int base = 0; base < cnt; base += 8) {
            int idx = 0;
            if (base + g8 < cnt) idx = sorted[e0 + base + g8];
            int m = cnt - base; if (m > 8) m = 8;
            int j = 0;
            for (; j + 4 <= m; j += 4) {
                int s0 = __shfl(idx, j, 8);
                int s1 = __shfl(idx, j + 1, 8);
                int s2 = __shfl(idx, j + 2, 8);
                int s3 = __shfl(idx, j + 3, 8);
                uint4 u0 = *(const uint4*)(H + (size_t)s0 * 256 + c0);
                uint4 u1 = *(const uint4*)(H + (size_t)s1 * 256 + c0);
                uint4 u2 = *(const uint4*)(H + (size_t)s2 * 256 + c0);
                uint4 u3 = *(const uint4*)(H + (size_t)s3 * 256 + c0);
                ACC8(u0); ACC8(u1); ACC8(u2); ACC8(u3);
            }
            for (; j < m; j++) {
                int s = __shfl(idx, j, 8);
                uint4 u = *(const uint4*)(H + (size_t)s * 256 + c0);
                ACC8(u);
            }
        }
        float dn = dinv[n];
        float o[8];
        #pragma unroll
        for (int j = 0; j < 8; j++) o[j] = acc[j] * dn + bv[j];
        float4 w0 = {o[0], o[1], o[2], o[3]};
        float4 w1 = {o[4], o[5], o[6], o[7]};
        *(float4*)(Out + (size_t)n * kOUT + c0) = w0;
        *(float4*)(Out + (size_t)n * kOUT + c0 + 4) = w1;
        #pragma unroll
        for (int j = 0; j < 8; j++) {
            atomicAdd(&ss[c0 + j], o[j]);
            atomicAdd(&ss[64 + c0 + j], o[j] * o[j]);
        }
    }
    __syncthreads();
    if (t < 64)  atomicAdd(&stats[256 + t], ss[t]);
    else if (t < 128) atomicAdd(&stats[320 + (t - 64)], ss[t]);
}

__global__ void k_out(const float* __restrict__ A2, const float* __restrict__ stats,
                      const int* __restrict__ batch, const void* __restrict__ gamma,
                      const void* __restrict__ beta, const int* __restrict__ flags,
                      bf16_t* __restrict__ out) {
    int wid = threadIdx.x >> 6;
    int lane = threadIdx.x & 63;
    int i = blockIdx.x * 4 + wid;
    if (i >= kNB) return;
    int n = batch[i];
    int c = lane;
    float mu = stats[256 + c] * (1.f / kNN);
    float var = stats[320 + c] * (1.f / kNN) - mu * mu;
    float g, b;
    if (flags[0]) { g = bf2f(((const bf16_t*)gamma)[c]); b = bf2f(((const bf16_t*)beta)[c]); }
    else          { g = ((const float*)gamma)[c];        b = ((const float*)beta)[c]; }
    float v = (A2[(size_t)n * kOUT + c] - mu) * rsqrtf(var + kEPS) * g + b;
    v = v > 0.f ? v : 0.f;
    float m = v;
    for (int o = 32; o; o >>= 1) m = fmaxf(m, __shfl_xor(m, o));
    float ex = expf(v - m);
    float s = ex;
    for (int o = 32; o; o >>= 1) s += __shfl_xor(s, o);
    float r = v - m - logf(s);
    if (flags[0]) out[(size_t)i * kOUT + c] = f2bf(r);
    else ((float*)out)[(size_t)i * kOUT + c] = r;
}

static inline size_t align_up(size_t x, size_t a) { return (x + a - 1) & ~(a - 1); }

extern "C" void kernel_launch(void* const* d_in, const int* in_sizes, int n_in,
                              void* d_out, int out_size, void* d_ws, size_t ws_size,
                              hipStream_t stream) {
    (void)in_sizes; (void)n_in; (void)out_size; (void)ws_size;
    const void* feat = d_in[0];
    const int* ei    = (const int*)d_in[1];
    const int* batch = (const int*)d_in[2];
    const void* W1   = d_in[3];
    const void* b1   = d_in[4];
    const void* g1   = d_in[5];
    const void* be1  = d_in[6];
    const void* W2   = d_in[7];
    const void* b2   = d_in[8];
    const void* g2   = d_in[9];
    const void* be2  = d_in[10];

    char* ws = (char*)d_ws;
    size_t o = 0;
    int*          flags  = (int*)(ws + o);          o = align_up(o + 32, 256);
    unsigned int* deg    = (unsigned int*)(ws + o); o = align_up(o + (size_t)kNN * 4, 256);
    float*        dinv   = (float*)(ws + o);        o = align_up(o + (size_t)kNN * 4, 256);
    unsigned int* cursor = (unsigned int*)(ws + o); o = align_up(o + (size_t)kNN * 4, 256);
    float*        stats  = (float*)(ws + o);        o = align_up(o + 384 * 4, 256);
    float*        bnp    = (float*)(ws + o);        o = align_up(o + 256 * 4, 256);
    int*          sorted = (int*)(ws + o);          o = align_up(o + (size_t)kNE * 4, 256);
    bf16_t*       h1     = (bf16_t*)(ws + o);       o = align_up(o + (size_t)kNN * kHID * 2, 256);
    float*        a1     = (float*)(ws + o);        o = align_up(o + (size_t)kNN * kHID * 4, 256);
    bf16_t*       wz1    = (bf16_t*)(ws + o);       o = align_up(o + (size_t)8 * 8 * 64 * 8 * 2, 256);
    bf16_t*       wz2    = (bf16_t*)(ws + o);       o = align_up(o + (size_t)4 * 4 * 64 * 8 * 2, 256);

    // build-phase aliases (dead before hosts are written, stream-ordered):
    unsigned int* pairs  = (unsigned int*)h1;                         // 6.4MB < 25.6MB
    unsigned int* counts = (unsigned int*)a1;                         // 306KB
    unsigned int* offm   = (unsigned int*)((char*)a1 + 512 * 1024);   // 306KB
    unsigned int* gbase  = (unsigned int*)((char*)a1 + 1024 * 1024);  // 788B

    bf16_t*       h2 = (bf16_t*)a1;     // embedded: row n at a1 + n*512B (written by gemm2 after reading)
    float*        a2 = (float*)h1;      // h1 dead after agg1; 25.6MB exact fit

    bf16_t* outp = (bf16_t*)d_out;

    // graph build (two-level multisplit) + weight pre-swizzle
    k_probe   <<<1, 64, 0, stream>>>((const uint32_t*)feat, (const uint32_t*)ei, flags);
    k_prepw   <<<20, 256, 0, stream>>>(W1, W2, flags, wz1, wz2);
    k_hist1   <<<kNBLK, 256, 0, stream>>>(ei, flags, counts);
    k_scanA   <<<1, 256, 0, stream>>>(counts, gbase, stats);
    k_scanB   <<<kNBUK, 64, 0, stream>>>(counts, gbase, offm);
    k_scatter1<<<kNBLK, 256, 0, stream>>>(ei, flags, offm, pairs);
    k_scatter2<<<kNBUK, 1024, 0, stream>>>(pairs, gbase, deg, dinv, cursor, sorted);

    // layer 1
    k_gemm1 <<<(kNN + 127) / 128, 256, 0, stream>>>(feat, wz1, dinv, h1, flags);
    k_agg1  <<<2048, 256, 0, stream>>>(h1, sorted, cursor, deg, dinv, b1, flags, a1, stats);
    k_bnprep<<<1, 128, 0, stream>>>(stats, g1, be1, flags, bnp);

    // layer 2 (BN1+ReLU fused into GEMM A-operand)
    k_gemm2<<<(kNN + 127) / 128, 256, 0, stream>>>(a1, wz2, dinv, bnp, h2);
    k_agg2 <<<1024, 256, 0, stream>>>(h2, sorted, cursor, deg, dinv, b2, flags, a2, stats);

    // gather + BN2 + relu + log_softmax
    k_out<<<(kNB + 3) / 4, 256, 0, stream>>>(a2, stats, batch, g2, be2, flags, outp);
}

// Round 5
// 477.846 us; speedup vs baseline: 1.1241x; 1.1241x over previous
//
#include <hip/hip_runtime.h>
#include <stdint.h>

typedef unsigned short bf16_t;

constexpr int kNN   = 100000;
constexpr int kNE   = 1600000;
constexpr int kFEAT = 256;
constexpr int kHID  = 128;
constexpr int kOUT  = 64;
constexpr int kNB   = 10000;
constexpr float kEPS = 1e-5f;

constexpr int kEPB  = 4096;                       // edges per hist/scatter block
constexpr int kNBLK = (kNE + kEPB - 1) / kEPB;    // 391
constexpr int kNBUK = (kNN + 511) / 512;          // 196 coarse buckets (512 nodes each)

typedef __attribute__((ext_vector_type(8))) short short8v;
typedef __attribute__((ext_vector_type(4))) float f32x4;

__device__ __forceinline__ float bf2f(bf16_t u) {
    union { uint32_t i; float f; } v; v.i = ((uint32_t)u) << 16; return v.f;
}
__device__ __forceinline__ bf16_t f2bf(float f) {
    uint32_t u = __float_as_uint(f);
    uint32_t r = (u + 0x7FFFu + ((u >> 16) & 1u)) >> 16;
    return (bf16_t)r;
}
__device__ __forceinline__ float lo16(uint32_t u) {
    union { uint32_t i; float f; } v; v.i = u << 16; return v.f;
}
__device__ __forceinline__ float hi16(uint32_t u) {
    union { uint32_t i; float f; } v; v.i = u & 0xFFFF0000u; return v.f;
}

// flags[0]: 1 if float tensors are bf16, 0 if fp32.  flags[1]: 1 if edge_index int64.
__global__ void k_probe(const uint32_t* __restrict__ feat, const uint32_t* __restrict__ ei,
                        int* __restrict__ flags) {
    int l = threadIdx.x;   // 64 lanes
    int good = 0;
    for (int j = l; j < 256; j += 64) {
        uint32_t e = (feat[j] >> 7) & 0xFFu;
        if (e >= 100u && e <= 132u) good++;
    }
    for (int o = 32; o; o >>= 1) good += __shfl_xor(good, o);
    int zeros = 0;
    for (int j = l; j < 128; j += 64) zeros += (ei[2 * j + 1] == 0u) ? 1 : 0;
    for (int o = 32; o; o >>= 1) zeros += __shfl_xor(zeros, o);
    if (l == 0) {
        flags[0] = (good > 128) ? 1 : 0;
        flags[1] = (zeros > 64) ? 1 : 0;
    }
}

// -------- graph build: two-level multisplit (no global atomics) --------

__global__ void k_hist1(const int* __restrict__ ei, const int* __restrict__ flags,
                        unsigned int* __restrict__ counts) {
    __shared__ unsigned int lh[kNBUK];
    int t = threadIdx.x;
    for (int i = t; i < kNBUK; i += 256) lh[i] = 0u;
    __syncthreads();
    int i64 = flags[1];
    int base = blockIdx.x * kEPB;
    for (int k = 0; k < 16; k++) {
        int e = base + k * 256 + t;
        if (e < kNE) {
            int d = i64 ? ei[2 * (kNE + e)] : ei[kNE + e];
            atomicAdd(&lh[d >> 9], 1u);
        }
    }
    __syncthreads();
    for (int i = t; i < kNBUK; i += 256) counts[(size_t)i * kNBLK + blockIdx.x] = lh[i];
}

// bucket totals -> exclusive bases; also zero stats
__global__ void k_scanA(const unsigned int* __restrict__ counts, unsigned int* __restrict__ base,
                        float* __restrict__ stats) {
    __shared__ unsigned int ss[256];
    int t = threadIdx.x;
    for (int i = t; i < 384; i += 256) stats[i] = 0.f;
    unsigned int tot = 0u;
    if (t < kNBUK) {
        const unsigned int* row = counts + (size_t)t * kNBLK;
        for (int j = 0; j < kNBLK; j++) tot += row[j];
    }
    ss[t] = tot;
    __syncthreads();
    for (int o = 1; o < 256; o <<= 1) {
        unsigned int x = (t >= o) ? ss[t - o] : 0u;
        __syncthreads();
        ss[t] += x;
        __syncthreads();
    }
    if (t < kNBUK) base[t] = ss[t] - tot;   // exclusive
    if (t == 0) base[kNBUK] = ss[255];      // == kNE
}

// per-(bucket,block) offsets
__global__ void k_scanB(const unsigned int* __restrict__ counts, const unsigned int* __restrict__ base,
                        unsigned int* __restrict__ off) {
    __shared__ unsigned int ss[64];
    int b = blockIdx.x, t = threadIdx.x;
    unsigned int run = base[b];
    for (int c0 = 0; c0 < kNBLK; c0 += 64) {
        int idx = c0 + t;
        unsigned int v = (idx < kNBLK) ? counts[(size_t)b * kNBLK + idx] : 0u;
        ss[t] = v;
        __syncthreads();
        for (int o = 1; o < 64; o <<= 1) {
            unsigned int x = (t >= o) ? ss[t - o] : 0u;
            __syncthreads();
            ss[t] += x;
            __syncthreads();
        }
        if (idx < kNBLK) off[(size_t)b * kNBLK + idx] = run + ss[t] - v;
        unsigned int ctot = ss[63];
        __syncthreads();
        run += ctot;
    }
}

// coarse scatter: packed (src | dlocal<<17), bucket-grouped runs, LDS cursors only
__global__ void k_scatter1(const int* __restrict__ ei, const int* __restrict__ flags,
                           const unsigned int* __restrict__ off, unsigned int* __restrict__ pairs) {
    __shared__ unsigned int lcur[kNBUK];
    int t = threadIdx.x;
    for (int i = t; i < kNBUK; i += 256) lcur[i] = off[(size_t)i * kNBLK + blockIdx.x];
    __syncthreads();
    int i64 = flags[1];
    int base = blockIdx.x * kEPB;
    for (int k = 0; k < 16; k++) {
        int e = base + k * 256 + t;
        if (e < kNE) {
            int s, d;
            if (i64) { s = ei[2 * e]; d = ei[2 * (kNE + e)]; }
            else     { s = ei[e];     d = ei[kNE + e]; }
            unsigned int p = atomicAdd(&lcur[d >> 9], 1u);
            pairs[p] = (unsigned int)s | ((unsigned int)(d & 511) << 17);
        }
    }
}

// fine scatter: one block per bucket; exact per-node CSR + deg/dinv/cursor
__global__ void __launch_bounds__(1024) k_scatter2(const unsigned int* __restrict__ pairs,
                        const unsigned int* __restrict__ base, unsigned int* __restrict__ deg,
                        float* __restrict__ dinv, unsigned int* __restrict__ cursor,
                        int* __restrict__ sorted) {
    __shared__ unsigned int hist[512], sc[512], lcur[512];
    int b = blockIdx.x, t = threadIdx.x;
    unsigned int gb = base[b];
    int cnt = (int)(base[b + 1] - gb);
    if (t < 512) hist[t] = 0u;
    __syncthreads();
    for (int i = t; i < cnt; i += 1024) atomicAdd(&hist[pairs[gb + i] >> 17], 1u);
    __syncthreads();
    if (t < 512) sc[t] = hist[t];
    __syncthreads();
    for (int o = 1; o < 512; o <<= 1) {
        unsigned int x = 0u;
        if (t < 512 && t >= o) x = sc[t - o];
        __syncthreads();
        if (t < 512) sc[t] += x;
        __syncthreads();
    }
    if (t < 512) {
        lcur[t] = gb + sc[t] - hist[t];
        int node = b * 512 + t;
        if (node < kNN) {
            unsigned int dg = hist[t] + 1u;   // + self loop
            deg[node] = dg;
            dinv[node] = rsqrtf((float)dg);
            cursor[node] = gb + sc[t];        // end of node's slice
        }
    }
    __syncthreads();
    for (int i = t; i < cnt; i += 1024) {
        unsigned int pk = pairs[gb + i];
        unsigned int slot = atomicAdd(&lcur[pk >> 17], 1u);
        sorted[slot] = (int)(pk & 0x1FFFFu);
    }
}

// -------- weights pre-swizzle (merged W1 + W2) --------
__global__ void k_prepw(const void* __restrict__ W1, const void* __restrict__ W2,
                        const int* __restrict__ flags, bf16_t* __restrict__ Wz1,
                        bf16_t* __restrict__ Wz2) {
    int gid = blockIdx.x * 256 + threadIdx.x;
    int isbf = flags[0];
    if (gid < 4096) {                 // W1: 8 k-steps x 8 n-frags x 64 lanes
        int idx = gid;
        int l = idx & 63, j = (idx >> 6) & 7, t = idx >> 9;
        int col = j * 16 + (l & 15);
        int kb = t * 32 + (l >> 4) * 8;
        bf16_t o[8];
        if (isbf) {
            const bf16_t* Wb = (const bf16_t*)W1;
            #pragma unroll
            for (int i = 0; i < 8; i++) o[i] = Wb[(size_t)(kb + i) * kHID + col];
        } else {
            const float* Wf = (const float*)W1;
            #pragma unroll
            for (int i = 0; i < 8; i++) o[i] = f2bf(Wf[(size_t)(kb + i) * kHID + col]);
        }
        uint4 w;
        w.x = (uint32_t)o[0] | ((uint32_t)o[1] << 16);
        w.y = (uint32_t)o[2] | ((uint32_t)o[3] << 16);
        w.z = (uint32_t)o[4] | ((uint32_t)o[5] << 16);
        w.w = (uint32_t)o[6] | ((uint32_t)o[7] << 16);
        *(uint4*)(Wz1 + (size_t)idx * 8) = w;
    } else if (gid < 4096 + 1024) {   // W2: 4 k-steps x 4 n-frags x 64 lanes
        int idx = gid - 4096;
        int l = idx & 63, j = (idx >> 6) & 3, t = idx >> 8;
        int col = j * 16 + (l & 15);
        int kb = t * 32 + (l >> 4) * 8;
        bf16_t o[8];
        if (isbf) {
            const bf16_t* Wb = (const bf16_t*)W2;
            #pragma unroll
            for (int i = 0; i < 8; i++) o[i] = Wb[(size_t)(kb + i) * kOUT + col];
        } else {
            const float* Wf = (const float*)W2;
            #pragma unroll
            for (int i = 0; i < 8; i++) o[i] = f2bf(Wf[(size_t)(kb + i) * kOUT + col]);
        }
        uint4 w;
        w.x = (uint32_t)o[0] | ((uint32_t)o[1] << 16);
        w.y = (uint32_t)o[2] | ((uint32_t)o[3] << 16);
        w.z = (uint32_t)o[4] | ((uint32_t)o[5] << 16);
        w.w = (uint32_t)o[6] | ((uint32_t)o[7] << 16);
        *(uint4*)(Wz2 + (size_t)idx * 8) = w;
    }
}

// -------- layer 1 GEMM (MFMA): H = dinv * (A @ W1), bf16 out --------
__global__ void k_gemm1(const void* __restrict__ A, const bf16_t* __restrict__ Wz,
                        const float* __restrict__ dinv, bf16_t* __restrict__ H,
                        const int* __restrict__ flags) {
    int isbf = flags[0];
    int wv = threadIdx.x >> 6;
    int l  = threadIdx.x & 63;
    int kgrp = l >> 4;
    int rbase = blockIdx.x * 128 + wv * 32;
    int arow0 = rbase + (l & 15);
    int arow1 = arow0 + 16;
    const bf16_t* Ab = (const bf16_t*)A;
    const float*  Af = (const float*)A;
    const short8v* Wv = (const short8v*)Wz;

    f32x4 acc[2][8];
    #pragma unroll
    for (int m = 0; m < 2; m++)
        #pragma unroll
        for (int j = 0; j < 8; j++)
            acc[m][j] = (f32x4){0.f, 0.f, 0.f, 0.f};

    #pragma unroll
    for (int t = 0; t < 8; t++) {
        int kbase = t * 32 + kgrp * 8;
        short8v a0, a1;
        #pragma unroll
        for (int i = 0; i < 8; i++) { a0[i] = 0; a1[i] = 0; }
        if (arow0 < kNN) {
            if (isbf) {
                a0 = *(const short8v*)(Ab + (size_t)arow0 * kFEAT + kbase);
            } else {
                const float* p = Af + (size_t)arow0 * kFEAT + kbase;
                #pragma unroll
                for (int i = 0; i < 8; i++) a0[i] = (short)f2bf(p[i]);
            }
        }
        if (arow1 < kNN) {
            if (isbf) {
                a1 = *(const short8v*)(Ab + (size_t)arow1 * kFEAT + kbase);
            } else {
                const float* p = Af + (size_t)arow1 * kFEAT + kbase;
                #pragma unroll
                for (int i = 0; i < 8; i++) a1[i] = (short)f2bf(p[i]);
            }
        }
        #pragma unroll
        for (int j = 0; j < 8; j++) {
            short8v b = Wv[(t * 8 + j) * 64 + l];
            acc[0][j] = __builtin_amdgcn_mfma_f32_16x16x32_bf16(a0, b, acc[0][j], 0, 0, 0);
            acc[1][j] = __builtin_amdgcn_mfma_f32_16x16x32_bf16(a1, b, acc[1][j], 0, 0, 0);
        }
    }

    #pragma unroll
    for (int m = 0; m < 2; m++) {
        #pragma unroll
        for (int r = 0; r < 4; r++) {
            int orow = rbase + m * 16 + kgrp * 4 + r;
            if (orow < kNN) {
                float dn = dinv[orow];
                bf16_t* hp = H + (size_t)orow * kHID + (l & 15);
                #pragma unroll
                for (int j = 0; j < 8; j++) hp[j * 16] = f2bf(acc[m][j][r] * dn);
            }
        }
    }
}

// A1 = dinv*(sum_src H[s] + H[n]) + b1, fused BN stats.
// One 64-lane wave per node (lane = dword = 2 ch), full-row coalesced gathers,
// unroll 8, grid-stride; per-block LDS stat reduction.
__global__ void k_agg1(const bf16_t* __restrict__ H, const int* __restrict__ sorted,
                       const unsigned int* __restrict__ cursor, const unsigned int* __restrict__ deg,
                       const float* __restrict__ dinv, const void* __restrict__ bias,
                       const int* __restrict__ flags, float* __restrict__ Out,
                       float* __restrict__ stats) {
    __shared__ float ss[256];   // [0..128) sum, [128..256) sumsq
    int t = threadIdx.x;
    ss[t] = 0.f;
    int wv = t >> 6;
    int lane = t & 63;
    int c0 = lane * 2;
    float b0, b1v;
    if (flags[0]) { b0 = bf2f(((const bf16_t*)bias)[c0]); b1v = bf2f(((const bf16_t*)bias)[c0 + 1]); }
    else          { b0 = ((const float*)bias)[c0];        b1v = ((const float*)bias)[c0 + 1]; }
    const uint32_t* Hrow = (const uint32_t*)H;   // 64 words/row
    float ps0 = 0.f, ps1 = 0.f, pq0 = 0.f, pq1 = 0.f;
    for (int n = blockIdx.x * 4 + wv; n < kNN; n += gridDim.x * 4) {
        float dn = dinv[n];
        uint32_t hu = Hrow[(size_t)n * 64 + lane];
        float acc0 = lo16(hu), acc1 = hi16(hu);
        unsigned int e1 = cursor[n];
        int cnt = (int)(deg[n] - 1u);
        unsigned int e = e1 - (unsigned int)cnt;
        for (; cnt >= 8; cnt -= 8, e += 8) {
            int s0 = sorted[e],     s1 = sorted[e + 1], s2 = sorted[e + 2], s3 = sorted[e + 3];
            int s4 = sorted[e + 4], s5 = sorted[e + 5], s6 = sorted[e + 6], s7 = sorted[e + 7];
            uint32_t u0 = Hrow[(size_t)s0 * 64 + lane];
            uint32_t u1 = Hrow[(size_t)s1 * 64 + lane];
            uint32_t u2 = Hrow[(size_t)s2 * 64 + lane];
            uint32_t u3 = Hrow[(size_t)s3 * 64 + lane];
            uint32_t u4 = Hrow[(size_t)s4 * 64 + lane];
            uint32_t u5 = Hrow[(size_t)s5 * 64 + lane];
            uint32_t u6 = Hrow[(size_t)s6 * 64 + lane];
            uint32_t u7 = Hrow[(size_t)s7 * 64 + lane];
            acc0 += lo16(u0) + lo16(u1) + lo16(u2) + lo16(u3)
                  + lo16(u4) + lo16(u5) + lo16(u6) + lo16(u7);
            acc1 += hi16(u0) + hi16(u1) + hi16(u2) + hi16(u3)
                  + hi16(u4) + hi16(u5) + hi16(u6) + hi16(u7);
        }
        for (; cnt > 0; cnt--, e++) {
            uint32_t u = Hrow[(size_t)sorted[e] * 64 + lane];
            acc0 += lo16(u);
            acc1 += hi16(u);
        }
        float ox = acc0 * dn + b0;
        float oy = acc1 * dn + b1v;
        float2 o; o.x = ox; o.y = oy;
        *(float2*)(Out + (size_t)n * kHID + c0) = o;
        ps0 += ox; ps1 += oy; pq0 += ox * ox; pq1 += oy * oy;
    }
    __syncthreads();
    atomicAdd(&ss[c0], ps0);
    atomicAdd(&ss[c0 + 1], ps1);
    atomicAdd(&ss[128 + c0], pq0);
    atomicAdd(&ss[128 + c0 + 1], pq1);
    __syncthreads();
    atomicAdd(&stats[t], ss[t]);
}

// fold BN1 stats into per-channel scale/shift
__global__ void k_bnprep(const float* __restrict__ stats, const void* __restrict__ gamma,
                         const void* __restrict__ beta, const int* __restrict__ flags,
                         float* __restrict__ bnp) {
    int c = threadIdx.x;   // 128
    float mu = stats[c] * (1.f / kNN);
    float var = stats[128 + c] * (1.f / kNN) - mu * mu;
    float rs = rsqrtf(var + kEPS);
    float g, b;
    if (flags[0]) { g = bf2f(((const bf16_t*)gamma)[c]); b = bf2f(((const bf16_t*)beta)[c]); }
    else          { g = ((const float*)gamma)[c];        b = ((const float*)beta)[c]; }
    float sc = rs * g;
    bnp[c] = sc;
    bnp[128 + c] = b - mu * sc;
}

// layer 2 GEMM with fused BN1+ReLU on the fly. Reads a1 (fp32), writes h2 rows
// embedded at a1 row starts (each wave reads exactly the rows it later writes).
__global__ void k_gemm2(const float* A, const bf16_t* __restrict__ Wz,
                        const float* __restrict__ dinv, const float* __restrict__ bnp,
                        bf16_t* H /* = (bf16_t*)A, row stride 256 elems */) {
    int wv = threadIdx.x >> 6;
    int l  = threadIdx.x & 63;
    int kgrp = l >> 4;
    int rbase = blockIdx.x * 128 + wv * 32;
    int arow0 = rbase + (l & 15);
    int arow1 = arow0 + 16;
    const short8v* Wv = (const short8v*)Wz;

    f32x4 acc[2][4];
    #pragma unroll
    for (int m = 0; m < 2; m++)
        #pragma unroll
        for (int j = 0; j < 4; j++)
            acc[m][j] = (f32x4){0.f, 0.f, 0.f, 0.f};

    #pragma unroll
    for (int t = 0; t < 4; t++) {
        int kbase = t * 32 + kgrp * 8;
        float4 sa = *(const float4*)(bnp + kbase);
        float4 sb = *(const float4*)(bnp + kbase + 4);
        float4 ha = *(const float4*)(bnp + 128 + kbase);
        float4 hb = *(const float4*)(bnp + 128 + kbase + 4);
        short8v a0, a1;
        #pragma unroll
        for (int i = 0; i < 8; i++) { a0[i] = 0; a1[i] = 0; }
        if (arow0 < kNN) {
            float4 f0 = *(const float4*)(A + (size_t)arow0 * kHID + kbase);
            float4 f1 = *(const float4*)(A + (size_t)arow0 * kHID + kbase + 4);
            float v;
            v = f0.x * sa.x + ha.x; a0[0] = (short)f2bf(v > 0.f ? v : 0.f);
            v = f0.y * sa.y + ha.y; a0[1] = (short)f2bf(v > 0.f ? v : 0.f);
            v = f0.z * sa.z + ha.z; a0[2] = (short)f2bf(v > 0.f ? v : 0.f);
            v = f0.w * sa.w + ha.w; a0[3] = (short)f2bf(v > 0.f ? v : 0.f);
            v = f1.x * sb.x + hb.x; a0[4] = (short)f2bf(v > 0.f ? v : 0.f);
            v = f1.y * sb.y + hb.y; a0[5] = (short)f2bf(v > 0.f ? v : 0.f);
            v = f1.z * sb.z + hb.z; a0[6] = (short)f2bf(v > 0.f ? v : 0.f);
            v = f1.w * sb.w + hb.w; a0[7] = (short)f2bf(v > 0.f ? v : 0.f);
        }
        if (arow1 < kNN) {
            float4 f0 = *(const float4*)(A + (size_t)arow1 * kHID + kbase);
            float4 f1 = *(const float4*)(A + (size_t)arow1 * kHID + kbase + 4);
            float v;
            v = f0.x * sa.x + ha.x; a1[0] = (short)f2bf(v > 0.f ? v : 0.f);
            v = f0.y * sa.y + ha.y; a1[1] = (short)f2bf(v > 0.f ? v : 0.f);
            v = f0.z * sa.z + ha.z; a1[2] = (short)f2bf(v > 0.f ? v : 0.f);
            v = f0.w * sa.w + ha.w; a1[3] = (short)f2bf(v > 0.f ? v : 0.f);
            v = f1.x * sb.x + hb.x; a1[4] = (short)f2bf(v > 0.f ? v : 0.f);
            v = f1.y * sb.y + hb.y; a1[5] = (short)f2bf(v > 0.f ? v : 0.f);
            v = f1.z * sb.z + hb.z; a1[6] = (short)f2bf(v > 0.f ? v : 0.f);
            v = f1.w * sb.w + hb.w; a1[7] = (short)f2bf(v > 0.f ? v : 0.f);
        }
        #pragma unroll
        for (int j = 0; j < 4; j++) {
            short8v b = Wv[(t * 4 + j) * 64 + l];
            acc[0][j] = __builtin_amdgcn_mfma_f32_16x16x32_bf16(a0, b, acc[0][j], 0, 0, 0);
            acc[1][j] = __builtin_amdgcn_mfma_f32_16x16x32_bf16(a1, b, acc[1][j], 0, 0, 0);
        }
    }

    #pragma unroll
    for (int m = 0; m < 2; m++) {
        #pragma unroll
        for (int r = 0; r < 4; r++) {
            int orow = rbase + m * 16 + kgrp * 4 + r;
            if (orow < kNN) {
                float dn = dinv[orow];
                bf16_t* hp = H + (size_t)orow * 256 + (l & 15);   // stride 256 elems = a1 row
                #pragma unroll
                for (int j = 0; j < 4; j++) hp[j * 16] = f2bf(acc[m][j][r] * dn);
            }
        }
    }
}

// layer-2 aggregation: one 32-lane group per node (lane = dword), embedded h2
// rows (stride 256 elems), unroll 8, grid-stride, fused BN2 stats.
__global__ void k_agg2(const bf16_t* __restrict__ H, const int* __restrict__ sorted,
                       const unsigned int* __restrict__ cursor, const unsigned int* __restrict__ deg,
                       const float* __restrict__ dinv, const void* __restrict__ bias,
                       const int* __restrict__ flags, float* __restrict__ Out,
                       float* __restrict__ stats) {
    __shared__ float ss[128];   // [0..64) sum, [64..128) sumsq
    int t = threadIdx.x;
    if (t < 128) ss[t] = 0.f;
    int grp = t >> 5;           // 8 nodes per block-tile
    int lane = t & 31;
    int c0 = lane * 2;
    float b0, b1v;
    if (flags[0]) { b0 = bf2f(((const bf16_t*)bias)[c0]); b1v = bf2f(((const bf16_t*)bias)[c0 + 1]); }
    else          { b0 = ((const float*)bias)[c0];        b1v = ((const float*)bias)[c0 + 1]; }
    const uint32_t* Hrow = (const uint32_t*)H;   // 128 words/row (embedded), 32 used
    float ps0 = 0.f, ps1 = 0.f, pq0 = 0.f, pq1 = 0.f;
    for (int n = blockIdx.x * 8 + grp; n < kNN; n += gridDim.x * 8) {
        float dn = dinv[n];
        uint32_t hu = Hrow[(size_t)n * 128 + lane];
        float acc0 = lo16(hu), acc1 = hi16(hu);
        unsigned int e1 = cursor[n];
        int cnt = (int)(deg[n] - 1u);
        unsigned int e = e1 - (unsigned int)cnt;
        for (; cnt >= 8; cnt -= 8, e += 8) {
            int s0 = sorted[e],     s1 = sorted[e + 1], s2 = sorted[e + 2], s3 = sorted[e + 3];
            int s4 = sorted[e + 4], s5 = sorted[e + 5], s6 = sorted[e + 6], s7 = sorted[e + 7];
            uint32_t u0 = Hrow[(size_t)s0 * 128 + lane];
            uint32_t u1 = Hrow[(size_t)s1 * 128 + lane];
            uint32_t u2 = Hrow[(size_t)s2 * 128 + lane];
            uint32_t u3 = Hrow[(size_t)s3 * 128 + lane];
            uint32_t u4 = Hrow[(size_t)s4 * 128 + lane];
            uint32_t u5 = Hrow[(size_t)s5 * 128 + lane];
            uint32_t u6 = Hrow[(size_t)s6 * 128 + lane];
            uint32_t u7 = Hrow[(size_t)s7 * 128 + lane];
            acc0 += lo16(u0) + lo16(u1) + lo16(u2) + lo16(u3)
                  + lo16(u4) + lo16(u5) + lo16(u6) + lo16(u7);
            acc1 += hi16(u0) + hi16(u1) + hi16(u2) + hi16(u3)
                  + hi16(u4) + hi16(u5) + hi16(u6) + hi16(u7);
        }
        for (; cnt > 0; cnt--, e++) {
            uint32_t u = Hrow[(size_t)sorted[e] * 128 + lane];
            acc0 += lo16(u);
            acc1 += hi16(u);
        }
        float ox = acc0 * dn + b0;
        float oy = acc1 * dn + b1v;
        float2 o; o.x = ox; o.y = oy;
        *(float2*)(Out + (size_t)n * kOUT + c0) = o;
        ps0 += ox; ps1 += oy; pq0 += ox * ox; pq1 += oy * oy;
    }
    __syncthreads();
    atomicAdd(&ss[c0], ps0);
    atomicAdd(&ss[c0 + 1], ps1);
    atomicAdd(&ss[64 + c0], pq0);
    atomicAdd(&ss[64 + c0 + 1], pq1);
    __syncthreads();
    if (t < 64)  atomicAdd(&stats[256 + t], ss[t]);
    else if (t < 128) atomicAdd(&stats[320 + (t - 64)], ss[t]);
}

__global__ void k_out(const float* __restrict__ A2, const float* __restrict__ stats,
                      const int* __restrict__ batch, const void* __restrict__ gamma,
                      const void* __restrict__ beta, const int* __restrict__ flags,
                      bf16_t* __restrict__ out) {
    int wid = threadIdx.x >> 6;
    int lane = threadIdx.x & 63;
    int i = blockIdx.x * 4 + wid;
    if (i >= kNB) return;
    int n = batch[i];
    int c = lane;
    float mu = stats[256 + c] * (1.f / kNN);
    float var = stats[320 + c] * (1.f / kNN) - mu * mu;
    float g, b;
    if (flags[0]) { g = bf2f(((const bf16_t*)gamma)[c]); b = bf2f(((const bf16_t*)beta)[c]); }
    else          { g = ((const float*)gamma)[c];        b = ((const float*)beta)[c]; }
    float v = (A2[(size_t)n * kOUT + c] - mu) * rsqrtf(var + kEPS) * g + b;
    v = v > 0.f ? v : 0.f;
    float m = v;
    for (int o = 32; o; o >>= 1) m = fmaxf(m, __shfl_xor(m, o));
    float ex = expf(v - m);
    float s = ex;
    for (int o = 32; o; o >>= 1) s += __shfl_xor(s, o);
    float r = v - m - logf(s);
    if (flags[0]) out[(size_t)i * kOUT + c] = f2bf(r);
    else ((float*)out)[(size_t)i * kOUT + c] = r;
}

static inline size_t align_up(size_t x, size_t a) { return (x + a - 1) & ~(a - 1); }

extern "C" void kernel_launch(void* const* d_in, const int* in_sizes, int n_in,
                              void* d_out, int out_size, void* d_ws, size_t ws_size,
                              hipStream_t stream) {
    (void)in_sizes; (void)n_in; (void)out_size; (void)ws_size;
    const void* feat = d_in[0];
    const int* ei    = (const int*)d_in[1];
    const int* batch = (const int*)d_in[2];
    const void* W1   = d_in[3];
    const void* b1   = d_in[4];
    const void* g1   = d_in[5];
    const void* be1  = d_in[6];
    const void* W2   = d_in[7];
    const void* b2   = d_in[8];
    const void* g2   = d_in[9];
    const void* be2  = d_in[10];

    char* ws = (char*)d_ws;
    size_t o = 0;
    int*          flags  = (int*)(ws + o);          o = align_up(o + 32, 256);
    unsigned int* deg    = (unsigned int*)(ws + o); o = align_up(o + (size_t)kNN * 4, 256);
    float*        dinv   = (float*)(ws + o);        o = align_up(o + (size_t)kNN * 4, 256);
    unsigned int* cursor = (unsigned int*)(ws + o); o = align_up(o + (size_t)kNN * 4, 256);
    float*        stats  = (float*)(ws + o);        o = align_up(o + 384 * 4, 256);
    float*        bnp    = (float*)(ws + o);        o = align_up(o + 256 * 4, 256);
    int*          sorted = (int*)(ws + o);          o = align_up(o + (size_t)kNE * 4, 256);
    bf16_t*       h1     = (bf16_t*)(ws + o);       o = align_up(o + (size_t)kNN * kHID * 2, 256);
    float*        a1     = (float*)(ws + o);        o = align_up(o + (size_t)kNN * kHID * 4, 256);
    bf16_t*       wz1    = (bf16_t*)(ws + o);       o = align_up(o + (size_t)8 * 8 * 64 * 8 * 2, 256);
    bf16_t*       wz2    = (bf16_t*)(ws + o);       o = align_up(o + (size_t)4 * 4 * 64 * 8 * 2, 256);

    // build-phase aliases (dead before hosts are written, stream-ordered):
    unsigned int* pairs  = (unsigned int*)h1;                         // 6.4MB < 25.6MB
    unsigned int* counts = (unsigned int*)a1;                         // 306KB
    unsigned int* offm   = (unsigned int*)((char*)a1 + 512 * 1024);   // 306KB
    unsigned int* gbase  = (unsigned int*)((char*)a1 + 1024 * 1024);  // 788B

    bf16_t*       h2 = (bf16_t*)a1;     // embedded: row n at a1 + n*512B (written by gemm2 after reading)
    float*        a2 = (float*)h1;      // h1 dead after agg1; 25.6MB exact fit

    bf16_t* outp = (bf16_t*)d_out;

    // graph build (two-level multisplit) + weight pre-swizzle
    k_probe   <<<1, 64, 0, stream>>>((const uint32_t*)feat, (const uint32_t*)ei, flags);
    k_prepw   <<<20, 256, 0, stream>>>(W1, W2, flags, wz1, wz2);
    k_hist1   <<<kNBLK, 256, 0, stream>>>(ei, flags, counts);
    k_scanA   <<<1, 256, 0, stream>>>(counts, gbase, stats);
    k_scanB   <<<kNBUK, 64, 0, stream>>>(counts, gbase, offm);
    k_scatter1<<<kNBLK, 256, 0, stream>>>(ei, flags, offm, pairs);
    k_scatter2<<<kNBUK, 1024, 0, stream>>>(pairs, gbase, deg, dinv, cursor, sorted);

    // layer 1
    k_gemm1 <<<(kNN + 127) / 128, 256, 0, stream>>>(feat, wz1, dinv, h1, flags);
    k_agg1  <<<2048, 256, 0, stream>>>(h1, sorted, cursor, deg, dinv, b1, flags, a1, stats);
    k_bnprep<<<1, 128, 0, stream>>>(stats, g1, be1, flags, bnp);

    // layer 2 (BN1+ReLU fused into GEMM A-operand)
    k_gemm2<<<(kNN + 127) / 128, 256, 0, stream>>>(a1, wz2, dinv, bnp, h2);
    k_agg2 <<<1024, 256, 0, stream>>>(h2, sorted, cursor, deg, dinv, b2, flags, a2, stats);

    // gather + BN2 + relu + log_softmax
    k_out<<<(kNB + 3) / 4, 256, 0, stream>>>(a2, stats, batch, g2, be2, flags, outp);
}